// Round 1
// baseline (850.889 us; speedup 1.0000x reference)
//
#include <hip/hip_runtime.h>

#define B_    2
#define T_    2048
#define NH_   16
#define NKV_  4
#define HD_   128
#define RANK_ 512
#define DIM_  2048
#define BT_   (B_*T_)
#define EPS_  1.1920928955078125e-07f

typedef __bf16 bf16x8 __attribute__((ext_vector_type(8)));
typedef float  f32x4  __attribute__((ext_vector_type(4)));

__device__ inline unsigned short f2bf(float f) {
    unsigned int u = __float_as_uint(f);
    u += 0x7fff + ((u >> 16) & 1);   // round-to-nearest-even
    return (unsigned short)(u >> 16);
}

// ---------------------------------------------------------------- f32 -> bf16
__global__ __launch_bounds__(256) void cvt_kernel(const float* __restrict__ in,
                                                  unsigned short* __restrict__ out,
                                                  int n4) {
    int i = blockIdx.x * 256 + threadIdx.x;
    if (i < n4) {
        float4 v = ((const float4*)in)[i];
        ushort4 o;
        o.x = f2bf(v.x); o.y = f2bf(v.y); o.z = f2bf(v.z); o.w = f2bf(v.w);
        ((ushort4*)out)[i] = o;
    }
}

// ---------------------------------------------------------------- GEMM C = A * W^T
// A: M x K bf16 row-major, W: N x K bf16 row-major, C: M x N (f32 or bf16)
__device__ inline void store_out(float* p, float v) { *p = v; }
__device__ inline void store_out(unsigned short* p, float v) { *p = f2bf(v); }

template <typename OT>
__global__ __launch_bounds__(256) void gemm_bt(const unsigned short* __restrict__ A,
                                               const unsigned short* __restrict__ W,
                                               OT* __restrict__ C,
                                               int M, int N, int K) {
    __shared__ unsigned short As[128][40];   // pad 32->40: 80B row stride, 2-way max
    __shared__ unsigned short Ws[128][40];
    int tid  = threadIdx.x;
    int lane = tid & 63, wave = tid >> 6;
    int quad = lane >> 4, l16 = lane & 15;
    int wm = (wave >> 1) * 64, wn = (wave & 1) * 64;
    long m0 = (long)blockIdx.y * 128, n0 = (long)blockIdx.x * 128;
    int lr = tid >> 2;          // 0..63
    int lc = (tid & 3) * 8;     // 0,8,16,24

    f32x4 acc[4][4];
#pragma unroll
    for (int i = 0; i < 4; i++)
#pragma unroll
        for (int j = 0; j < 4; j++) acc[i][j] = (f32x4){0.f, 0.f, 0.f, 0.f};

    for (int k0 = 0; k0 < K; k0 += 32) {
        uint4 a0 = *(const uint4*)&A[(m0 + lr) * K + k0 + lc];
        uint4 a1 = *(const uint4*)&A[(m0 + 64 + lr) * K + k0 + lc];
        uint4 w0 = *(const uint4*)&W[(n0 + lr) * K + k0 + lc];
        uint4 w1 = *(const uint4*)&W[(n0 + 64 + lr) * K + k0 + lc];
        __syncthreads();
        *(uint4*)&As[lr][lc]      = a0;
        *(uint4*)&As[64 + lr][lc] = a1;
        *(uint4*)&Ws[lr][lc]      = w0;
        *(uint4*)&Ws[64 + lr][lc] = w1;
        __syncthreads();
        bf16x8 af[4], wf[4];
#pragma unroll
        for (int i = 0; i < 4; i++) af[i] = *(const bf16x8*)&As[wm + i * 16 + l16][quad * 8];
#pragma unroll
        for (int j = 0; j < 4; j++) wf[j] = *(const bf16x8*)&Ws[wn + j * 16 + l16][quad * 8];
#pragma unroll
        for (int i = 0; i < 4; i++)
#pragma unroll
            for (int j = 0; j < 4; j++)
                acc[i][j] = __builtin_amdgcn_mfma_f32_16x16x32_bf16(af[i], wf[j], acc[i][j], 0, 0, 0);
    }
#pragma unroll
    for (int i = 0; i < 4; i++)
#pragma unroll
        for (int j = 0; j < 4; j++)
#pragma unroll
            for (int r = 0; r < 4; r++) {
                long row = m0 + wm + i * 16 + quad * 4 + r;
                long col = n0 + wn + j * 16 + l16;
                store_out(&C[row * N + col], acc[i][j][r]);
            }
}

// ---------------------------------------------------------------- RMS-norm + RoPE (+gain)
// lin: (BT, incols) f32, head slice at h*128. out: (B, NHEADS, T, 128) bf16.
template <int NHEADS, bool GAIN>
__global__ __launch_bounds__(256) void qk_prep(const float* __restrict__ lin,
                                               const float* __restrict__ gain,
                                               unsigned short* __restrict__ out,
                                               int incols) {
    int r    = blockIdx.x * 4 + (threadIdx.x >> 6);
    int lane = threadIdx.x & 63;
    int bt = r / NHEADS, h = r % NHEADS;
    const float* ip = lin + (long)bt * incols + h * 128;
    float x1 = ip[lane], x2 = ip[lane + 64];
    float ss = x1 * x1 + x2 * x2;
#pragma unroll
    for (int off = 32; off; off >>= 1) ss += __shfl_xor(ss, off);
    float inv = rsqrtf(ss * (1.0f / 128.0f) + EPS_);
    x1 *= inv; x2 *= inv;
    int b = bt / T_, t = bt % T_;
    float freq = expf(-(float)lane * 0.14391156463f);   // ln(10000)/64
    float f = (float)t * freq;
    float s, c;
    sincosf(f, &s, &c);
    float g = GAIN ? gain[h] : 1.0f;
    float o1 = (x1 * c + x2 * s) * g;
    float o2 = (x2 * c - x1 * s) * g;
    unsigned short* op = out + ((long)(b * NHEADS + h) * T_ + t) * 128;
    op[lane]      = f2bf(o1);
    op[lane + 64] = f2bf(o2);
}

// ---------------------------------------------------------------- V transpose: (BT,512) f32 -> (B,NKV,128,T) bf16
__global__ __launch_bounds__(256) void v_transpose(const float* __restrict__ vlin,
                                                   unsigned short* __restrict__ vt) {
    __shared__ float tile[32][33];
    int bkv = blockIdx.z, b = bkv >> 2, kv = bkv & 3;
    int t0 = blockIdx.x * 32, d0 = blockIdx.y * 32;
    int tx = threadIdx.x & 31, ty = threadIdx.x >> 5;
#pragma unroll
    for (int rr = 0; rr < 32; rr += 8) {
        int t = t0 + ty + rr;
        tile[ty + rr][tx] = vlin[((long)(b * T_ + t)) * 512 + kv * 128 + d0 + tx];
    }
    __syncthreads();
#pragma unroll
    for (int rr = 0; rr < 32; rr += 8) {
        int d = d0 + ty + rr;
        vt[((long)((b * NKV_ + kv) * 128 + d)) * T_ + t0 + tx] = f2bf(tile[tx][ty + rr]);
    }
}

// ---------------------------------------------------------------- flash attention (causal, GQA)
// Q: (B,NH,T,128) bf16; K: (B,NKV,T,128) bf16; Vt: (B,NKV,128,T) bf16; Y: (B,T,NH*128) bf16
__global__ __launch_bounds__(256) void attn_kernel(const unsigned short* __restrict__ Q,
                                                   const unsigned short* __restrict__ Km,
                                                   const unsigned short* __restrict__ Vt,
                                                   unsigned short* __restrict__ Y) {
    __shared__ unsigned short Pld[4][16][72];   // per-wave P tile, padded
    int tid = threadIdx.x, lane = tid & 63, wave = tid >> 6;
    int quad = lane >> 4, l16 = lane & 15;
    int bh = blockIdx.y, b = bh >> 4, h = bh & 15, kv = h >> 2;
    int q0 = blockIdx.x * 64 + wave * 16;

    const unsigned short* qp = Q  + ((long)(b * NH_  + h ) * T_) * 128;
    const unsigned short* kp = Km + ((long)(b * NKV_ + kv) * T_) * 128;
    const unsigned short* vp = Vt + ((long)(b * NKV_ + kv) * 128) * (long)T_;

    bf16x8 qf[4];
#pragma unroll
    for (int s = 0; s < 4; s++)
        qf[s] = *(const bf16x8*)&qp[(q0 + l16) * 128 + s * 32 + quad * 8];

    f32x4 o[8];
#pragma unroll
    for (int n = 0; n < 8; n++) o[n] = (f32x4){0.f, 0.f, 0.f, 0.f};
    float mr[4], lsum[4];
#pragma unroll
    for (int r = 0; r < 4; r++) { mr[r] = -3.0e38f; lsum[r] = 0.f; }
    const float scale = 0.08838834764831845f;   // 1/sqrt(128)

    int nkt = blockIdx.x + 1;   // same for all 4 waves -> __syncthreads is safe
    for (int kt = 0; kt < nkt; kt++) {
        int tb = kt * 64;
        f32x4 sc[4];
#pragma unroll
        for (int j = 0; j < 4; j++) sc[j] = (f32x4){0.f, 0.f, 0.f, 0.f};
#pragma unroll
        for (int j = 0; j < 4; j++)
#pragma unroll
            for (int s = 0; s < 4; s++) {
                bf16x8 kf = *(const bf16x8*)&kp[(tb + j * 16 + l16) * 128 + s * 32 + quad * 8];
                sc[j] = __builtin_amdgcn_mfma_f32_16x16x32_bf16(qf[s], kf, sc[j], 0, 0, 0);
            }
        // online softmax per row (row = q0 + quad*4 + r, cols distributed over 16 lanes x 4 j-tiles)
#pragma unroll
        for (int r = 0; r < 4; r++) {
            int row = q0 + quad * 4 + r;
            float vj[4];
#pragma unroll
            for (int j = 0; j < 4; j++) {
                int col = tb + j * 16 + l16;
                vj[j] = (col <= row) ? sc[j][r] * scale : -3.0e38f;
            }
            float vmax = fmaxf(fmaxf(vj[0], vj[1]), fmaxf(vj[2], vj[3]));
#pragma unroll
            for (int off = 1; off < 16; off <<= 1) vmax = fmaxf(vmax, __shfl_xor(vmax, off));
            float mnew  = fmaxf(mr[r], vmax);
            float alpha = __expf(mr[r] - mnew);
            float psum  = 0.f;
#pragma unroll
            for (int j = 0; j < 4; j++) {
                float pv = __expf(vj[j] - mnew);
                psum += pv;
                Pld[wave][quad * 4 + r][j * 16 + l16] = f2bf(pv);
            }
#pragma unroll
            for (int off = 1; off < 16; off <<= 1) psum += __shfl_xor(psum, off);
            lsum[r] = lsum[r] * alpha + psum;
            mr[r]   = mnew;
#pragma unroll
            for (int n = 0; n < 8; n++) o[n][r] *= alpha;
        }
        __syncthreads();
        bf16x8 pf0 = *(const bf16x8*)&Pld[wave][l16][quad * 8];
        bf16x8 pf1 = *(const bf16x8*)&Pld[wave][l16][32 + quad * 8];
#pragma unroll
        for (int n = 0; n < 8; n++) {
            bf16x8 vf0 = *(const bf16x8*)&vp[(long)(n * 16 + l16) * T_ + tb + quad * 8];
            bf16x8 vf1 = *(const bf16x8*)&vp[(long)(n * 16 + l16) * T_ + tb + 32 + quad * 8];
            o[n] = __builtin_amdgcn_mfma_f32_16x16x32_bf16(pf0, vf0, o[n], 0, 0, 0);
            o[n] = __builtin_amdgcn_mfma_f32_16x16x32_bf16(pf1, vf1, o[n], 0, 0, 0);
        }
        __syncthreads();
    }
    // epilogue: Y[b][t][h*128 + d]
    unsigned short* yp = Y + ((long)b * T_) * DIM_ + h * 128;
    float rinv[4];
#pragma unroll
    for (int r = 0; r < 4; r++) rinv[r] = 1.0f / lsum[r];
#pragma unroll
    for (int n = 0; n < 8; n++)
#pragma unroll
        for (int r = 0; r < 4; r++) {
            int trow = q0 + quad * 4 + r;
            yp[(long)trow * DIM_ + n * 16 + l16] = f2bf(o[n][r] * rinv[r]);
        }
}

// ---------------------------------------------------------------- launch
extern "C" void kernel_launch(void* const* d_in, const int* in_sizes, int n_in,
                              void* d_out, int out_size, void* d_ws, size_t ws_size,
                              hipStream_t stream) {
    const float* x     = (const float*)d_in[0];
    const float* Wq    = (const float*)d_in[1];
    const float* Wdown = (const float*)d_in[2];
    const float* Wkup  = (const float*)d_in[3];
    const float* Wvup  = (const float*)d_in[4];
    const float* Wproj = (const float*)d_in[5];
    const float* qgain = (const float*)d_in[6];

    char* ws = (char*)d_ws;
    size_t off = 0;
    auto alloc = [&](size_t bytes) -> void* {
        void* p = ws + off;
        off += (bytes + 255) & ~(size_t)255;
        return p;
    };
    unsigned short* x_bf  = (unsigned short*)alloc((size_t)BT_ * DIM_ * 2);
    unsigned short* Wq_bf = (unsigned short*)alloc((size_t)DIM_ * DIM_ * 2);
    unsigned short* Wd_bf = (unsigned short*)alloc((size_t)RANK_ * DIM_ * 2);
    unsigned short* Wk_bf = (unsigned short*)alloc((size_t)512 * RANK_ * 2);
    unsigned short* Wv_bf = (unsigned short*)alloc((size_t)512 * RANK_ * 2);
    unsigned short* Wp_bf = (unsigned short*)alloc((size_t)DIM_ * DIM_ * 2);
    float*          q_lin = (float*)alloc((size_t)BT_ * DIM_ * 4);
    unsigned short* lat_bf= (unsigned short*)alloc((size_t)BT_ * RANK_ * 2);
    float*          k_lin = (float*)alloc((size_t)BT_ * 512 * 4);
    float*          v_lin = (float*)alloc((size_t)BT_ * 512 * 4);
    unsigned short* q_bf  = (unsigned short*)alloc((size_t)BT_ * DIM_ * 2);
    unsigned short* k_bf  = (unsigned short*)alloc((size_t)B_ * NKV_ * T_ * 128 * 2);
    unsigned short* vT_bf = (unsigned short*)alloc((size_t)B_ * NKV_ * T_ * 128 * 2);
    unsigned short* y_bf  = (unsigned short*)alloc((size_t)BT_ * DIM_ * 2);

    auto cvt = [&](const float* in, unsigned short* out, int n) {
        cvt_kernel<<<(n / 4 + 255) / 256, 256, 0, stream>>>(in, out, n / 4);
    };
    cvt(x,     x_bf,  BT_ * DIM_);
    cvt(Wq,    Wq_bf, DIM_ * DIM_);
    cvt(Wdown, Wd_bf, RANK_ * DIM_);
    cvt(Wkup,  Wk_bf, 512 * RANK_);
    cvt(Wvup,  Wv_bf, 512 * RANK_);
    cvt(Wproj, Wp_bf, DIM_ * DIM_);

    gemm_bt<float><<<dim3(DIM_ / 128, BT_ / 128), 256, 0, stream>>>(x_bf, Wq_bf, q_lin, BT_, DIM_, DIM_);
    gemm_bt<unsigned short><<<dim3(RANK_ / 128, BT_ / 128), 256, 0, stream>>>(x_bf, Wd_bf, lat_bf, BT_, RANK_, DIM_);
    gemm_bt<float><<<dim3(512 / 128, BT_ / 128), 256, 0, stream>>>(lat_bf, Wk_bf, k_lin, BT_, 512, RANK_);
    gemm_bt<float><<<dim3(512 / 128, BT_ / 128), 256, 0, stream>>>(lat_bf, Wv_bf, v_lin, BT_, 512, RANK_);

    qk_prep<NH_, true><<<BT_ * NH_ / 4, 256, 0, stream>>>(q_lin, qgain, q_bf, DIM_);
    qk_prep<NKV_, false><<<BT_ * NKV_ / 4, 256, 0, stream>>>(k_lin, qgain, k_bf, 512);
    v_transpose<<<dim3(T_ / 32, 128 / 32, B_ * NKV_), 256, 0, stream>>>(v_lin, vT_bf);

    attn_kernel<<<dim3(T_ / 64, B_ * NH_), 256, 0, stream>>>(q_bf, k_bf, vT_bf, y_bf);

    gemm_bt<float><<<dim3(DIM_ / 128, BT_ / 128), 256, 0, stream>>>(y_bf, Wp_bf, (float*)d_out, BT_, DIM_, DIM_);
}

// Round 2
// 681.719 us; speedup vs baseline: 1.2482x; 1.2482x over previous
//
#include <hip/hip_runtime.h>
#include <stdint.h>

#define B_    2
#define T_    2048
#define NH_   16
#define NKV_  4
#define HD_   128
#define RANK_ 512
#define DIM_  2048
#define BT_   (B_*T_)
#define EPS_  1.1920928955078125e-07f

typedef __bf16 bf16x8 __attribute__((ext_vector_type(8)));
typedef float  f32x4  __attribute__((ext_vector_type(4)));

__device__ inline unsigned short f2bf(float f) {
    unsigned int u = __float_as_uint(f);
    u += 0x7fff + ((u >> 16) & 1);   // round-to-nearest-even
    return (unsigned short)(u >> 16);
}
__device__ inline float bf2f(unsigned short u) {
    return __uint_as_float(((unsigned int)u) << 16);
}

#define GLOAD_LDS16(gp, lp)                                                        \
    __builtin_amdgcn_global_load_lds(                                              \
        (const __attribute__((address_space(1))) void*)(gp),                       \
        (__attribute__((address_space(3))) void*)(lp), 16, 0, 0)

// ---------------------------------------------------------------- f32 -> bf16
__global__ __launch_bounds__(256) void cvt_kernel(const float* __restrict__ in,
                                                  unsigned short* __restrict__ out,
                                                  int n4) {
    int i = blockIdx.x * 256 + threadIdx.x;
    if (i < n4) {
        float4 v = ((const float4*)in)[i];
        ushort4 o;
        o.x = f2bf(v.x); o.y = f2bf(v.y); o.z = f2bf(v.z); o.w = f2bf(v.w);
        ((ushort4*)out)[i] = o;
    }
}

// ---------------------------------------------------------------- GEMM C = A * W^T
// m97 recipe: global_load_lds width=16 into UNPADDED [128][32] LDS.
__device__ inline void store_out(float* p, float v) { *p = v; }
__device__ inline void store_out(unsigned short* p, float v) { *p = f2bf(v); }

template <typename OT>
__global__ __launch_bounds__(256) void gemm_bt(const unsigned short* __restrict__ A,
                                               const unsigned short* __restrict__ W,
                                               OT* __restrict__ C,
                                               int M, int N, int K) {
    __shared__ unsigned short As[128][32];
    __shared__ unsigned short Ws[128][32];
    int tid  = threadIdx.x;
    int lane = tid & 63, wave = tid >> 6;
    int quad = lane >> 4, l16 = lane & 15;
    int wm = (wave >> 1) * 64, wn = (wave & 1) * 64;
    long m0 = (long)blockIdx.y * 128, n0 = (long)blockIdx.x * 128;

    // staging: wave w owns rows [w*32, w*32+32) of both tiles; lane l -> row w*32+l/4, col (l&3)*8
    int sr = wave * 32 + (lane >> 2);
    int scl = (lane & 3) * 8;
    const unsigned short* Ag0 = A + (m0 + sr) * K + scl;
    const unsigned short* Ag1 = A + (m0 + sr + 16) * K + scl;
    const unsigned short* Wg0 = W + (n0 + sr) * K + scl;
    const unsigned short* Wg1 = W + (n0 + sr + 16) * K + scl;
    unsigned short* Al0 = &As[wave * 32][0];
    unsigned short* Al1 = &As[wave * 32 + 16][0];
    unsigned short* Wl0 = &Ws[wave * 32][0];
    unsigned short* Wl1 = &Ws[wave * 32 + 16][0];

    f32x4 acc[4][4];
#pragma unroll
    for (int i = 0; i < 4; i++)
#pragma unroll
        for (int j = 0; j < 4; j++) acc[i][j] = (f32x4){0.f, 0.f, 0.f, 0.f};

    for (int k0 = 0; k0 < K; k0 += 32) {
        __syncthreads();                       // prior iter's LDS reads done
        GLOAD_LDS16(Ag0 + k0, Al0);
        GLOAD_LDS16(Ag1 + k0, Al1);
        GLOAD_LDS16(Wg0 + k0, Wl0);
        GLOAD_LDS16(Wg1 + k0, Wl1);
        __syncthreads();                       // staged data visible
        bf16x8 af[4], wf[4];
#pragma unroll
        for (int i = 0; i < 4; i++) af[i] = *(const bf16x8*)&As[wm + i * 16 + l16][quad * 8];
#pragma unroll
        for (int j = 0; j < 4; j++) wf[j] = *(const bf16x8*)&Ws[wn + j * 16 + l16][quad * 8];
#pragma unroll
        for (int i = 0; i < 4; i++)
#pragma unroll
            for (int j = 0; j < 4; j++)
                acc[i][j] = __builtin_amdgcn_mfma_f32_16x16x32_bf16(af[i], wf[j], acc[i][j], 0, 0, 0);
    }
#pragma unroll
    for (int i = 0; i < 4; i++)
#pragma unroll
        for (int j = 0; j < 4; j++)
#pragma unroll
            for (int r = 0; r < 4; r++) {
                long row = m0 + wm + i * 16 + quad * 4 + r;
                long col = n0 + wn + j * 16 + l16;
                store_out(&C[row * N + col], acc[i][j][r]);
            }
}

// ---------------------------------------------------------------- RMS-norm + RoPE (+gain, +score scale folded into Q)
template <int NHEADS, bool GAIN>
__global__ __launch_bounds__(256) void qk_prep(const float* __restrict__ lin,
                                               const float* __restrict__ gain,
                                               unsigned short* __restrict__ out,
                                               int incols) {
    int r    = blockIdx.x * 4 + (threadIdx.x >> 6);
    int lane = threadIdx.x & 63;
    int bt = r / NHEADS, h = r % NHEADS;
    const float* ip = lin + (long)bt * incols + h * 128;
    float x1 = ip[lane], x2 = ip[lane + 64];
    float ss = x1 * x1 + x2 * x2;
#pragma unroll
    for (int off = 32; off; off >>= 1) ss += __shfl_xor(ss, off);
    float inv = rsqrtf(ss * (1.0f / 128.0f) + EPS_);
    x1 *= inv; x2 *= inv;
    int b = bt / T_, t = bt % T_;
    float freq = expf(-(float)lane * 0.14391156463f);   // ln(10000)/64
    float f = (float)t * freq;
    float s, c;
    sincosf(f, &s, &c);
    float g = GAIN ? gain[h] * 0.08838834764831845f : 1.0f;  // fold 1/sqrt(128) into Q
    float o1 = (x1 * c + x2 * s) * g;
    float o2 = (x2 * c - x1 * s) * g;
    unsigned short* op = out + ((long)(b * NHEADS + h) * T_ + t) * 128;
    op[lane]      = f2bf(o1);
    op[lane + 64] = f2bf(o2);
}

// ---------------------------------------------------------------- V transpose: (BT,512) f32 -> (B,NKV,128,T) bf16
__global__ __launch_bounds__(256) void v_transpose(const float* __restrict__ vlin,
                                                   unsigned short* __restrict__ vt) {
    __shared__ float tile[32][33];
    int bkv = blockIdx.z, b = bkv >> 2, kv = bkv & 3;
    int t0 = blockIdx.x * 32, d0 = blockIdx.y * 32;
    int tx = threadIdx.x & 31, ty = threadIdx.x >> 5;
#pragma unroll
    for (int rr = 0; rr < 32; rr += 8) {
        int t = t0 + ty + rr;
        tile[ty + rr][tx] = vlin[((long)(b * T_ + t)) * 512 + kv * 128 + d0 + tx];
    }
    __syncthreads();
#pragma unroll
    for (int rr = 0; rr < 32; rr += 8) {
        int d = d0 + ty + rr;
        vt[((long)((b * NKV_ + kv) * 128 + d)) * T_ + t0 + tx] = f2bf(tile[tx][ty + rr]);
    }
}

// ---------------------------------------------------------------- flash attention, split-K, wave-independent
// Wave unit = (bh, i = 16-row q tile 0..127, chunk c of 8 kv tiles). No __syncthreads anywhere.
// Block packs 4 consecutive-i waves with identical (bh, c) for L1/L2 K/V reuse.
// Partials: po[slot][16][128] bf16 (unnormalized O), pm/pl[slot][16] f32.
// slot(bh,i,c) = bh*320 + 16*g*(g+1) + (i&31)*(g+1) + c,  g = i>>5.
__global__ __launch_bounds__(256) void attn_kernel(const unsigned short* __restrict__ Q,
                                                   const unsigned short* __restrict__ Km,
                                                   const unsigned short* __restrict__ Vt,
                                                   unsigned short* __restrict__ po,
                                                   float* __restrict__ pm,
                                                   float* __restrict__ pl) {
    __shared__ unsigned short Pld[4][16][72];   // wave-private slices
    int tid = threadIdx.x, lane = tid & 63, wave = tid >> 6;
    int quad = lane >> 4, l16 = lane & 15;

    int bh  = blockIdx.x / 80;
    int rem = blockIdx.x % 80;
    int g, loc;
    if      (rem <  8) { g = 0; loc = rem;      }
    else if (rem < 24) { g = 1; loc = rem - 8;  }
    else if (rem < 48) { g = 2; loc = rem - 24; }
    else               { g = 3; loc = rem - 48; }
    int ib = g * 8 + loc / (g + 1);
    int c  = loc - (loc / (g + 1)) * (g + 1);
    int i  = ib * 4 + wave;           // this wave's 16-row q tile
    int q0 = i * 16;
    int b = bh >> 4, h = bh & 15, kv = h >> 2;

    const unsigned short* qp = Q  + ((long)(b * NH_  + h ) * T_ + q0) * 128;
    const unsigned short* kp = Km + ((long)(b * NKV_ + kv) * T_) * 128;
    const unsigned short* vp = Vt + ((long)(b * NKV_ + kv) * 128) * (long)T_;

    bf16x8 qf[4];
#pragma unroll
    for (int s = 0; s < 4; s++)
        qf[s] = *(const bf16x8*)&qp[l16 * 128 + s * 32 + quad * 8];

    f32x4 o[8];
#pragma unroll
    for (int n = 0; n < 8; n++) o[n] = (f32x4){0.f, 0.f, 0.f, 0.f};
    float mr[4], ls[4];
#pragma unroll
    for (int r = 0; r < 4; r++) { mr[r] = -3.0e38f; ls[r] = 0.f; }

    int kt  = c * 8;
    int kte = min(kt + 8, ((q0 + 15) >> 6) + 1);
    for (; kt < kte; kt++) {
        int tb = kt * 64;
        f32x4 sc[4];
#pragma unroll
        for (int j = 0; j < 4; j++) sc[j] = (f32x4){0.f, 0.f, 0.f, 0.f};
#pragma unroll
        for (int j = 0; j < 4; j++)
#pragma unroll
            for (int s = 0; s < 4; s++) {
                bf16x8 kf = *(const bf16x8*)&kp[(long)(tb + j * 16 + l16) * 128 + s * 32 + quad * 8];
                sc[j] = __builtin_amdgcn_mfma_f32_16x16x32_bf16(qf[s], kf, sc[j], 0, 0, 0);
            }
#pragma unroll
        for (int r = 0; r < 4; r++) {
            int row = q0 + quad * 4 + r;
            float vj[4];
#pragma unroll
            for (int j = 0; j < 4; j++) {
                int col = tb + j * 16 + l16;
                vj[j] = (col <= row) ? sc[j][r] : -3.0e38f;   // scale pre-folded into Q
            }
            float vmax = fmaxf(fmaxf(vj[0], vj[1]), fmaxf(vj[2], vj[3]));
#pragma unroll
            for (int off = 1; off < 16; off <<= 1) vmax = fmaxf(vmax, __shfl_xor(vmax, off));
            float mnew  = fmaxf(mr[r], vmax);
            float alpha = __expf(mr[r] - mnew);
            float psum  = 0.f;
#pragma unroll
            for (int j = 0; j < 4; j++) {
                float pv = __expf(vj[j] - mnew);
                psum += pv;
                Pld[wave][quad * 4 + r][j * 16 + l16] = f2bf(pv);
            }
#pragma unroll
            for (int off = 1; off < 16; off <<= 1) psum += __shfl_xor(psum, off);
            ls[r] = ls[r] * alpha + psum;
            mr[r] = mnew;
#pragma unroll
            for (int n = 0; n < 8; n++) o[n][r] *= alpha;
        }
        __threadfence_block();   // wave-private LDS: order writes before reads (no barrier needed)
        bf16x8 pf0 = *(const bf16x8*)&Pld[wave][l16][quad * 8];
        bf16x8 pf1 = *(const bf16x8*)&Pld[wave][l16][32 + quad * 8];
#pragma unroll
        for (int n = 0; n < 8; n++) {
            bf16x8 vf0 = *(const bf16x8*)&vp[(long)(n * 16 + l16) * T_ + tb + quad * 8];
            bf16x8 vf1 = *(const bf16x8*)&vp[(long)(n * 16 + l16) * T_ + tb + 32 + quad * 8];
            o[n] = __builtin_amdgcn_mfma_f32_16x16x32_bf16(pf0, vf0, o[n], 0, 0, 0);
            o[n] = __builtin_amdgcn_mfma_f32_16x16x32_bf16(pf1, vf1, o[n], 0, 0, 0);
        }
        __threadfence_block();   // keep next iter's P writes behind these reads
    }

    int g2 = i >> 5;
    long slot = (long)bh * 320 + 16 * g2 * (g2 + 1) + (long)(i & 31) * (g2 + 1) + c;
    unsigned short* pob = po + slot * 2048;
#pragma unroll
    for (int n = 0; n < 8; n++)
#pragma unroll
        for (int r = 0; r < 4; r++)
            pob[(quad * 4 + r) * 128 + n * 16 + l16] = f2bf(o[n][r]);
    if (l16 == 0) {
#pragma unroll
        for (int r = 0; r < 4; r++) {
            pm[slot * 16 + quad * 4 + r] = mr[r];
            pl[slot * 16 + quad * 4 + r] = ls[r];
        }
    }
}

// ---------------------------------------------------------------- split-K combine -> Y (B,T,DIM) bf16
__global__ __launch_bounds__(256) void attn_combine(const unsigned short* __restrict__ po,
                                                    const float* __restrict__ pm,
                                                    const float* __restrict__ pl,
                                                    unsigned short* __restrict__ Y) {
    int bh = blockIdx.x >> 7, i = blockIdx.x & 127;
    int g2 = i >> 5, nc = g2 + 1;
    long slot0 = (long)bh * 320 + 16 * g2 * (g2 + 1) + (long)(i & 31) * nc;
    int col = threadIdx.x & 127;
    int r0  = threadIdx.x >> 7;        // 0..1
    int b = bh >> 4, h = bh & 15;
    for (int r = r0; r < 16; r += 2) {
        float M = -3.0e38f;
        for (int c = 0; c < nc; c++) M = fmaxf(M, pm[(slot0 + c) * 16 + r]);
        float L = 0.f, acc = 0.f;
        for (int c = 0; c < nc; c++) {
            float w = __expf(pm[(slot0 + c) * 16 + r] - M);
            L   += pl[(slot0 + c) * 16 + r] * w;
            acc += w * bf2f(po[(slot0 + c) * 2048 + r * 128 + col]);
        }
        Y[((long)b * T_ + i * 16 + r) * DIM_ + h * 128 + col] = f2bf(acc / L);
    }
}

// ---------------------------------------------------------------- launch
extern "C" void kernel_launch(void* const* d_in, const int* in_sizes, int n_in,
                              void* d_out, int out_size, void* d_ws, size_t ws_size,
                              hipStream_t stream) {
    const float* x     = (const float*)d_in[0];
    const float* Wq    = (const float*)d_in[1];
    const float* Wdown = (const float*)d_in[2];
    const float* Wkup  = (const float*)d_in[3];
    const float* Wvup  = (const float*)d_in[4];
    const float* Wproj = (const float*)d_in[5];
    const float* qgain = (const float*)d_in[6];

    char* ws = (char*)d_ws;
    size_t off = 0;
    auto alloc = [&](size_t bytes) -> void* {
        void* p = ws + off;
        off += (bytes + 255) & ~(size_t)255;
        return p;
    };
    unsigned short* x_bf  = (unsigned short*)alloc((size_t)BT_ * DIM_ * 2);
    unsigned short* Wq_bf = (unsigned short*)alloc((size_t)DIM_ * DIM_ * 2);
    unsigned short* Wd_bf = (unsigned short*)alloc((size_t)RANK_ * DIM_ * 2);
    unsigned short* Wk_bf = (unsigned short*)alloc((size_t)512 * RANK_ * 2);
    unsigned short* Wv_bf = (unsigned short*)alloc((size_t)512 * RANK_ * 2);
    unsigned short* Wp_bf = (unsigned short*)alloc((size_t)DIM_ * DIM_ * 2);
    float*          q_lin = (float*)alloc((size_t)BT_ * DIM_ * 4);     // dead after qk_prep
    unsigned short* lat_bf= (unsigned short*)alloc((size_t)BT_ * RANK_ * 2); // dead after gemm3/4
    float*          k_lin = (float*)alloc((size_t)BT_ * 512 * 4);      // dead after qk_prep
    float*          v_lin = (float*)alloc((size_t)BT_ * 512 * 4);      // dead after v_transpose
    unsigned short* q_bf  = (unsigned short*)alloc((size_t)BT_ * DIM_ * 2);
    unsigned short* k_bf  = (unsigned short*)alloc((size_t)B_ * NKV_ * T_ * 128 * 2);
    unsigned short* vT_bf = (unsigned short*)alloc((size_t)B_ * NKV_ * T_ * 128 * 2);
    unsigned short* y_bf  = (unsigned short*)alloc((size_t)BT_ * DIM_ * 2);

    // split-K partials reuse the dead q_lin..v_lin region (43.3 MB < 52 MB available)
    unsigned short* po = (unsigned short*)q_lin;                       // 10240*2048*2 = 41.9 MB
    float* pm = (float*)((char*)q_lin + (size_t)10240 * 2048 * 2);     // 655 KB
    float* pl = pm + 10240 * 16;                                       // 655 KB

    auto cvt = [&](const float* in, unsigned short* out, int n) {
        cvt_kernel<<<(n / 4 + 255) / 256, 256, 0, stream>>>(in, out, n / 4);
    };
    cvt(x,     x_bf,  BT_ * DIM_);
    cvt(Wq,    Wq_bf, DIM_ * DIM_);
    cvt(Wdown, Wd_bf, RANK_ * DIM_);
    cvt(Wkup,  Wk_bf, 512 * RANK_);
    cvt(Wvup,  Wv_bf, 512 * RANK_);
    cvt(Wproj, Wp_bf, DIM_ * DIM_);

    gemm_bt<float><<<dim3(DIM_ / 128, BT_ / 128), 256, 0, stream>>>(x_bf, Wq_bf, q_lin, BT_, DIM_, DIM_);
    gemm_bt<unsigned short><<<dim3(RANK_ / 128, BT_ / 128), 256, 0, stream>>>(x_bf, Wd_bf, lat_bf, BT_, RANK_, DIM_);
    gemm_bt<float><<<dim3(512 / 128, BT_ / 128), 256, 0, stream>>>(lat_bf, Wk_bf, k_lin, BT_, 512, RANK_);
    gemm_bt<float><<<dim3(512 / 128, BT_ / 128), 256, 0, stream>>>(lat_bf, Wv_bf, v_lin, BT_, 512, RANK_);

    qk_prep<NH_, true><<<BT_ * NH_ / 4, 256, 0, stream>>>(q_lin, qgain, q_bf, DIM_);
    qk_prep<NKV_, false><<<BT_ * NKV_ / 4, 256, 0, stream>>>(k_lin, qgain, k_bf, 512);
    v_transpose<<<dim3(T_ / 32, 128 / 32, B_ * NKV_), 256, 0, stream>>>(v_lin, vT_bf);

    attn_kernel<<<dim3(32 * 80), 256, 0, stream>>>(q_bf, k_bf, vT_bf, po, pm, pl);
    attn_combine<<<dim3(32 * 128), 256, 0, stream>>>(po, pm, pl, y_bf);

    gemm_bt<float><<<dim3(DIM_ / 128, BT_ / 128), 256, 0, stream>>>(y_bf, Wp_bf, (float*)d_out, BT_, DIM_, DIM_);
}

// Round 3
// 458.926 us; speedup vs baseline: 1.8541x; 1.4855x over previous
//
#include <hip/hip_runtime.h>
#include <stdint.h>

#define B_    2
#define T_    2048
#define NH_   16
#define NKV_  4
#define HD_   128
#define RANK_ 512
#define DIM_  2048
#define BT_   (B_*T_)
#define EPS_  1.1920928955078125e-07f

typedef __bf16 bf16x8 __attribute__((ext_vector_type(8)));
typedef float  f32x4  __attribute__((ext_vector_type(4)));

__device__ inline unsigned short f2bf(float f) {
    unsigned int u = __float_as_uint(f);
    u += 0x7fff + ((u >> 16) & 1);   // round-to-nearest-even
    return (unsigned short)(u >> 16);
}
__device__ inline float bf2f(unsigned short u) {
    return __uint_as_float(((unsigned int)u) << 16);
}

#define GLOAD_LDS16(gp, lp)                                                        \
    __builtin_amdgcn_global_load_lds(                                              \
        (const __attribute__((address_space(1))) void*)(gp),                       \
        (__attribute__((address_space(3))) void*)(lp), 16, 0, 0)

// ---------------------------------------------------------------- f32 -> bf16
__global__ __launch_bounds__(256) void cvt_kernel(const float* __restrict__ in,
                                                  unsigned short* __restrict__ out,
                                                  int n4) {
    int i = blockIdx.x * 256 + threadIdx.x;
    if (i < n4) {
        float4 v = ((const float4*)in)[i];
        ushort4 o;
        o.x = f2bf(v.x); o.y = f2bf(v.y); o.z = f2bf(v.z); o.w = f2bf(v.w);
        ((ushort4*)out)[i] = o;
    }
}

// ---------------------------------------------------------------- GEMM C = A * W^T
__device__ inline void store_out(float* p, float v) { *p = v; }
__device__ inline void store_out(unsigned short* p, float v) { *p = f2bf(v); }

template <typename OT>
__global__ __launch_bounds__(256) void gemm_bt(const unsigned short* __restrict__ A,
                                               const unsigned short* __restrict__ W,
                                               OT* __restrict__ C,
                                               int M, int N, int K) {
    __shared__ unsigned short As[128][32];
    __shared__ unsigned short Ws[128][32];
    int tid  = threadIdx.x;
    int lane = tid & 63, wave = tid >> 6;
    int quad = lane >> 4, l16 = lane & 15;
    int wm = (wave >> 1) * 64, wn = (wave & 1) * 64;
    long m0 = (long)blockIdx.y * 128, n0 = (long)blockIdx.x * 128;

    int sr = wave * 32 + (lane >> 2);
    int scl = (lane & 3) * 8;
    const unsigned short* Ag0 = A + (m0 + sr) * K + scl;
    const unsigned short* Ag1 = A + (m0 + sr + 16) * K + scl;
    const unsigned short* Wg0 = W + (n0 + sr) * K + scl;
    const unsigned short* Wg1 = W + (n0 + sr + 16) * K + scl;
    unsigned short* Al0 = &As[wave * 32][0];
    unsigned short* Al1 = &As[wave * 32 + 16][0];
    unsigned short* Wl0 = &Ws[wave * 32][0];
    unsigned short* Wl1 = &Ws[wave * 32 + 16][0];

    f32x4 acc[4][4];
#pragma unroll
    for (int i = 0; i < 4; i++)
#pragma unroll
        for (int j = 0; j < 4; j++) acc[i][j] = (f32x4){0.f, 0.f, 0.f, 0.f};

    for (int k0 = 0; k0 < K; k0 += 32) {
        __syncthreads();
        GLOAD_LDS16(Ag0 + k0, Al0);
        GLOAD_LDS16(Ag1 + k0, Al1);
        GLOAD_LDS16(Wg0 + k0, Wl0);
        GLOAD_LDS16(Wg1 + k0, Wl1);
        __syncthreads();
        bf16x8 af[4], wf[4];
#pragma unroll
        for (int i = 0; i < 4; i++) af[i] = *(const bf16x8*)&As[wm + i * 16 + l16][quad * 8];
#pragma unroll
        for (int j = 0; j < 4; j++) wf[j] = *(const bf16x8*)&Ws[wn + j * 16 + l16][quad * 8];
#pragma unroll
        for (int i = 0; i < 4; i++)
#pragma unroll
            for (int j = 0; j < 4; j++)
                acc[i][j] = __builtin_amdgcn_mfma_f32_16x16x32_bf16(af[i], wf[j], acc[i][j], 0, 0, 0);
    }
#pragma unroll
    for (int i = 0; i < 4; i++)
#pragma unroll
        for (int j = 0; j < 4; j++)
#pragma unroll
            for (int r = 0; r < 4; r++) {
                long row = m0 + wm + i * 16 + quad * 4 + r;
                long col = n0 + wn + j * 16 + l16;
                store_out(&C[row * N + col], acc[i][j][r]);
            }
}

// ---------------------------------------------------------------- RMS-norm + RoPE (+gain)
template <int NHEADS, bool GAIN>
__global__ __launch_bounds__(256) void qk_prep(const float* __restrict__ lin,
                                               const float* __restrict__ gain,
                                               unsigned short* __restrict__ out,
                                               int incols) {
    int r    = blockIdx.x * 4 + (threadIdx.x >> 6);
    int lane = threadIdx.x & 63;
    int bt = r / NHEADS, h = r % NHEADS;
    const float* ip = lin + (long)bt * incols + h * 128;
    float x1 = ip[lane], x2 = ip[lane + 64];
    float ss = x1 * x1 + x2 * x2;
#pragma unroll
    for (int off = 32; off; off >>= 1) ss += __shfl_xor(ss, off);
    float inv = rsqrtf(ss * (1.0f / 128.0f) + EPS_);
    x1 *= inv; x2 *= inv;
    int b = bt / T_, t = bt % T_;
    float freq = expf(-(float)lane * 0.14391156463f);   // ln(10000)/64
    float f = (float)t * freq;
    float s, c;
    sincosf(f, &s, &c);
    float g = GAIN ? gain[h] * 0.08838834764831845f : 1.0f;  // fold 1/sqrt(128) into Q
    float o1 = (x1 * c + x2 * s) * g;
    float o2 = (x2 * c - x1 * s) * g;
    unsigned short* op = out + ((long)(b * NHEADS + h) * T_ + t) * 128;
    op[lane]      = f2bf(o1);
    op[lane + 64] = f2bf(o2);
}

// ---------------------------------------------------------------- V transpose: kv_lin cols 512..1023 -> (B,NKV,128,T) bf16
__global__ __launch_bounds__(256) void v_transpose(const float* __restrict__ vlin,
                                                   unsigned short* __restrict__ vt) {
    __shared__ float tile[32][33];
    int bkv = blockIdx.z, b = bkv >> 2, kv = bkv & 3;
    int t0 = blockIdx.x * 32, d0 = blockIdx.y * 32;
    int tx = threadIdx.x & 31, ty = threadIdx.x >> 5;
#pragma unroll
    for (int rr = 0; rr < 32; rr += 8) {
        int t = t0 + ty + rr;
        tile[ty + rr][tx] = vlin[((long)(b * T_ + t)) * 1024 + 512 + kv * 128 + d0 + tx];
    }
    __syncthreads();
#pragma unroll
    for (int rr = 0; rr < 32; rr += 8) {
        int d = d0 + ty + rr;
        vt[((long)((b * NKV_ + kv) * 128 + d)) * T_ + t0 + tx] = f2bf(tile[tx][ty + rr]);
    }
}

// ---------------------------------------------------------------- flash attention
// Block = (bh, qb: 128 q rows, chunk c of 8 kv-tiles). 4 waves x 32 q rows.
// K,V staged once per tile into LDS (global_load_lds w=16); transposed scores S^T = K Q^T
// so softmax reduce = 15 VALU + 2 shfl; P^T lands in B-operand layout via padded LDS bounce.
// Partials per (bh, i2 = qb*4+w, c): po[slot][32][128] bf16, pm/pl[slot][32] f32.
__global__ __launch_bounds__(256, 3) void attn_kernel(const unsigned short* __restrict__ Q,
                                                      const unsigned short* __restrict__ Km,
                                                      const unsigned short* __restrict__ Vt,
                                                      unsigned short* __restrict__ po,
                                                      float* __restrict__ pm,
                                                      float* __restrict__ pl) {
    __shared__ alignas(16) unsigned short Ks2[4][64][32];   // [d-chunk s][kv row][d in chunk]
    __shared__ alignas(16) unsigned short Vs2[2][128][32];  // [kv-chunk h][d row][kv in chunk]
    __shared__ alignas(16) unsigned short Pt[4][32][72];    // per-wave P^T / O bounce, padded

    int tid = threadIdx.x, lane = tid & 63, wave = tid >> 6;
    int quad = lane >> 4, l16 = lane & 15;

    int bh  = blockIdx.x / 40;
    int rem = blockIdx.x % 40;
    int g, loc;
    if      (rem <  4) { g = 0; loc = rem;      }
    else if (rem < 12) { g = 1; loc = rem - 4;  }
    else if (rem < 24) { g = 2; loc = rem - 12; }
    else               { g = 3; loc = rem - 24; }
    int qb = g * 4 + loc / (g + 1);
    int c  = loc % (g + 1);
    int b = bh >> 4, h = bh & 15, kv = h >> 2;
    int Q0 = qb * 128 + wave * 32;

    int kt0 = c * 8;
    int nt  = min(kt0 * 8 + 64, (2 * qb + 2) * 8) / 8 - kt0;   // = min(kt0+8, 2qb+2) - kt0
    nt = min(8, 2 * qb + 2 - kt0);

    const unsigned short* qp = Q + ((long)(b * NH_ + h) * T_ + Q0) * 128;
    const char* kb = (const char*)(Km + (long)(b * NKV_ + kv) * T_ * 128);
    const char* vb = (const char*)(Vt + (long)(b * NKV_ + kv) * 128 * (long)T_);
    char* ksB = (char*)&Ks2[0][0][0];
    char* vsB = (char*)&Vs2[0][0][0];
    unsigned short* PtW = &Pt[wave][0][0];

    // Q fragments (B-operand), register-resident: Qf[u][s], u = q subtile, s = d chunk
    bf16x8 Qf[2][4];
#pragma unroll
    for (int u = 0; u < 2; u++)
#pragma unroll
        for (int s = 0; s < 4; s++)
            Qf[u][s] = *(const bf16x8*)&qp[(u * 16 + l16) * 128 + s * 32 + quad * 8];

    f32x4 Ot[8][2];
#pragma unroll
    for (int n = 0; n < 8; n++)
#pragma unroll
        for (int u = 0; u < 2; u++) Ot[n][u] = (f32x4){0.f, 0.f, 0.f, 0.f};
    float mr[2] = {-3.0e38f, -3.0e38f}, ls[2] = {0.f, 0.f};

    for (int kt = kt0; kt < kt0 + nt; kt++) {
        int tb = kt * 64;
        __syncthreads();   // prior tile's LDS reads done
        // stage K: wave = d-chunk s, 4 row-groups of 16
        {
            const char* kg = kb + (long)tb * 256 + wave * 64 + (lane >> 2) * 256 + (lane & 3) * 16;
            char* kl = ksB + wave * 4096 + lane * 16;
#pragma unroll
            for (int r = 0; r < 4; r++)
                GLOAD_LDS16(kg + r * 4096, kl + r * 1024);
        }
        // stage V: h = wave>>1, D base = (wave&1)*64 + r*16
        {
            int hh = wave >> 1;
            int D0 = (wave & 1) * 64;
            const char* vg = vb + (long)(D0 + (lane >> 3) * 0) * 0;  // (computed per round below)
#pragma unroll
            for (int r = 0; r < 4; r++) {
                int D = D0 + r * 16;
                const char* vgr = vb + (long)(D + (lane >> 2)) * 4096 + (long)tb * 2 + hh * 64 + (lane & 3) * 16;
                char* vl = vsB + hh * 8192 + D * 64 + lane * 16;
                GLOAD_LDS16(vgr, vl);
            }
        }
        __syncthreads();   // staged data visible (vmcnt drained by barrier)

        // S^T = K * Q^T : sc[j][u], j = kv subtile, u = q subtile
        f32x4 sc[4][2];
#pragma unroll
        for (int j = 0; j < 4; j++)
#pragma unroll
            for (int u = 0; u < 2; u++) sc[j][u] = (f32x4){0.f, 0.f, 0.f, 0.f};
#pragma unroll
        for (int j = 0; j < 4; j++)
#pragma unroll
            for (int s = 0; s < 4; s++) {
                bf16x8 kf = *(const bf16x8*)&Ks2[s][j * 16 + l16][quad * 8];
                sc[j][0] = __builtin_amdgcn_mfma_f32_16x16x32_bf16(kf, Qf[0][s], sc[j][0], 0, 0, 0);
                sc[j][1] = __builtin_amdgcn_mfma_f32_16x16x32_bf16(kf, Qf[1][s], sc[j][1], 0, 0, 0);
            }

        // online softmax per q subtile (reduction over kv = (j, quad, r))
#pragma unroll
        for (int u = 0; u < 2; u++) {
            if (tb + 63 > Q0 + u * 16) {            // wave-uniform: boundary tile, mask
                int qg = Q0 + u * 16 + l16;
#pragma unroll
                for (int j = 0; j < 4; j++)
#pragma unroll
                    for (int r = 0; r < 4; r++) {
                        int kvg = tb + j * 16 + quad * 4 + r;
                        if (kvg > qg) sc[j][u][r] = -3.0e38f;
                    }
            }
            float mx = -3.0e38f;
#pragma unroll
            for (int j = 0; j < 4; j++)
#pragma unroll
                for (int r = 0; r < 4; r++) mx = fmaxf(mx, sc[j][u][r]);
            mx = fmaxf(mx, __shfl_xor(mx, 16));
            mx = fmaxf(mx, __shfl_xor(mx, 32));
            float mnew  = fmaxf(mr[u], mx);
            float alpha = __expf(mr[u] - mnew);
            float ps = 0.f;
#pragma unroll
            for (int j = 0; j < 4; j++) {
                ushort4 pk;
                float p0 = __expf(sc[j][u][0] - mnew);
                float p1 = __expf(sc[j][u][1] - mnew);
                float p2 = __expf(sc[j][u][2] - mnew);
                float p3 = __expf(sc[j][u][3] - mnew);
                ps += (p0 + p1) + (p2 + p3);
                pk.x = f2bf(p0); pk.y = f2bf(p1); pk.z = f2bf(p2); pk.w = f2bf(p3);
                *(ushort4*)&PtW[(u * 16 + l16) * 72 + j * 16 + quad * 4] = pk;
            }
            ps += __shfl_xor(ps, 16);
            ps += __shfl_xor(ps, 32);
            ls[u] = ls[u] * alpha + ps;
            mr[u] = mnew;
#pragma unroll
            for (int n = 0; n < 8; n++) Ot[n][u] *= alpha;
        }
        __threadfence_block();   // P^T writes -> reads (wave-private LDS)

        // O^T += V^T * P^T
#pragma unroll
        for (int hh = 0; hh < 2; hh++) {
            bf16x8 pf0 = *(const bf16x8*)&PtW[(0 * 16 + l16) * 72 + hh * 32 + quad * 8];
            bf16x8 pf1 = *(const bf16x8*)&PtW[(1 * 16 + l16) * 72 + hh * 32 + quad * 8];
#pragma unroll
            for (int n = 0; n < 8; n++) {
                bf16x8 vf = *(const bf16x8*)&Vs2[hh][n * 16 + l16][quad * 8];
                Ot[n][0] = __builtin_amdgcn_mfma_f32_16x16x32_bf16(vf, pf0, Ot[n][0], 0, 0, 0);
                Ot[n][1] = __builtin_amdgcn_mfma_f32_16x16x32_bf16(vf, pf1, Ot[n][1], 0, 0, 0);
            }
        }
    }

    // epilogue: transpose O^T -> O rows via Pt, coalesced 16B stores of unnormalized O
    int i2 = qb * 4 + wave;
    long slot = (long)bh * 160 + 8 * g * (g + 1) + (long)(i2 & 15) * (g + 1) + c;
#pragma unroll
    for (int half = 0; half < 2; half++) {
        __threadfence_block();
#pragma unroll
        for (int n2 = 0; n2 < 4; n2++) {
            int n = half * 4 + n2;
#pragma unroll
            for (int u = 0; u < 2; u++) {
                ushort4 pk;
                pk.x = f2bf(Ot[n][u][0]); pk.y = f2bf(Ot[n][u][1]);
                pk.z = f2bf(Ot[n][u][2]); pk.w = f2bf(Ot[n][u][3]);
                *(ushort4*)&PtW[(u * 16 + l16) * 72 + n2 * 16 + quad * 4] = pk;
            }
        }
        __threadfence_block();
#pragma unroll
        for (int rr = 0; rr < 4; rr++) {
            int qrow = rr * 8 + (lane >> 3);
            int colseg = (lane & 7) * 8;
            uint4 val = *(const uint4*)&PtW[qrow * 72 + colseg];
            *(uint4*)&po[slot * 4096 + qrow * 128 + half * 64 + colseg] = val;
        }
    }
    if (lane < 16) {
        pm[slot * 32 + lane]      = mr[0];
        pm[slot * 32 + 16 + lane] = mr[1];
        pl[slot * 32 + lane]      = ls[0];
        pl[slot * 32 + 16 + lane] = ls[1];
    }
}

// ---------------------------------------------------------------- split-K combine -> Y (B,T,DIM) bf16
__global__ __launch_bounds__(256) void attn_combine(const unsigned short* __restrict__ po,
                                                    const float* __restrict__ pm,
                                                    const float* __restrict__ pl,
                                                    unsigned short* __restrict__ Y) {
    int bh = blockIdx.x >> 6, i2 = blockIdx.x & 63;
    int g = i2 >> 4, nc = g + 1;
    long slot0 = (long)bh * 160 + 8 * g * (g + 1) + (long)(i2 & 15) * nc;
    int col = threadIdx.x & 127;
    int r0  = threadIdx.x >> 7;
    int b = bh >> 4, h = bh & 15;
    for (int r = r0; r < 32; r += 2) {
        float M = -3.0e38f;
        for (int c = 0; c < nc; c++) M = fmaxf(M, pm[(slot0 + c) * 32 + r]);
        float L = 0.f, acc = 0.f;
        for (int c = 0; c < nc; c++) {
            float w = __expf(pm[(slot0 + c) * 32 + r] - M);
            L   += pl[(slot0 + c) * 32 + r] * w;
            acc += w * bf2f(po[(slot0 + c) * 4096 + r * 128 + col]);
        }
        Y[((long)b * T_ + i2 * 32 + r) * DIM_ + h * 128 + col] = f2bf(acc / L);
    }
}

// ---------------------------------------------------------------- launch
extern "C" void kernel_launch(void* const* d_in, const int* in_sizes, int n_in,
                              void* d_out, int out_size, void* d_ws, size_t ws_size,
                              hipStream_t stream) {
    const float* x     = (const float*)d_in[0];
    const float* Wq    = (const float*)d_in[1];
    const float* Wdown = (const float*)d_in[2];
    const float* Wkup  = (const float*)d_in[3];
    const float* Wvup  = (const float*)d_in[4];
    const float* Wproj = (const float*)d_in[5];
    const float* qgain = (const float*)d_in[6];

    char* ws = (char*)d_ws;
    size_t off = 0;
    auto alloc = [&](size_t bytes) -> void* {
        void* p = ws + off;
        off += (bytes + 255) & ~(size_t)255;
        return p;
    };
    unsigned short* x_bf   = (unsigned short*)alloc((size_t)BT_ * DIM_ * 2);
    unsigned short* Wq_bf  = (unsigned short*)alloc((size_t)DIM_ * DIM_ * 2);
    unsigned short* Wd_bf  = (unsigned short*)alloc((size_t)RANK_ * DIM_ * 2);
    unsigned short* Wkv_bf = (unsigned short*)alloc((size_t)1024 * RANK_ * 2);
    unsigned short* Wp_bf  = (unsigned short*)alloc((size_t)DIM_ * DIM_ * 2);
    float*          q_lin  = (float*)alloc((size_t)BT_ * DIM_ * 4);      // dead after qk_prep
    unsigned short* lat_bf = (unsigned short*)alloc((size_t)BT_ * RANK_ * 2);
    float*          kv_lin = (float*)alloc((size_t)BT_ * 1024 * 4);     // dead after preps
    unsigned short* q_bf   = (unsigned short*)alloc((size_t)BT_ * DIM_ * 2);
    unsigned short* k_bf   = (unsigned short*)alloc((size_t)B_ * NKV_ * T_ * 128 * 2);
    unsigned short* vT_bf  = (unsigned short*)alloc((size_t)B_ * NKV_ * T_ * 128 * 2);
    unsigned short* y_bf   = (unsigned short*)alloc((size_t)BT_ * DIM_ * 2);

    // split-K partials overlay the dead q_lin..kv_lin region (43.3 MB < 54.5 MB)
    unsigned short* po = (unsigned short*)q_lin;                        // 5120*4096*2 = 41.9 MB
    float* pm = (float*)((char*)q_lin + (size_t)5120 * 4096 * 2);       // 0.65 MB
    float* pl = pm + 5120 * 32;                                         // 0.65 MB

    auto cvt = [&](const float* in, unsigned short* out, int n) {
        cvt_kernel<<<(n / 4 + 255) / 256, 256, 0, stream>>>(in, out, n / 4);
    };
    cvt(x,     x_bf,  BT_ * DIM_);
    cvt(Wq,    Wq_bf, DIM_ * DIM_);
    cvt(Wdown, Wd_bf, RANK_ * DIM_);
    cvt(Wkup,  Wkv_bf,             512 * RANK_);
    cvt(Wvup,  Wkv_bf + 512 * RANK_, 512 * RANK_);
    cvt(Wproj, Wp_bf, DIM_ * DIM_);

    gemm_bt<float><<<dim3(DIM_ / 128, BT_ / 128), 256, 0, stream>>>(x_bf, Wq_bf, q_lin, BT_, DIM_, DIM_);
    gemm_bt<unsigned short><<<dim3(RANK_ / 128, BT_ / 128), 256, 0, stream>>>(x_bf, Wd_bf, lat_bf, BT_, RANK_, DIM_);
    gemm_bt<float><<<dim3(1024 / 128, BT_ / 128), 256, 0, stream>>>(lat_bf, Wkv_bf, kv_lin, BT_, 1024, RANK_);

    qk_prep<NH_, true><<<BT_ * NH_ / 4, 256, 0, stream>>>(q_lin, qgain, q_bf, DIM_);
    qk_prep<NKV_, false><<<BT_ * NKV_ / 4, 256, 0, stream>>>(kv_lin, qgain, k_bf, 1024);
    v_transpose<<<dim3(T_ / 32, 128 / 32, B_ * NKV_), 256, 0, stream>>>(kv_lin, vT_bf);

    attn_kernel<<<dim3(32 * 40), 256, 0, stream>>>(q_bf, k_bf, vT_bf, po, pm, pl);
    attn_combine<<<dim3(32 * 64), 256, 0, stream>>>(po, pm, pl, y_bf);

    gemm_bt<float><<<dim3(DIM_ / 128, BT_ / 128), 256, 0, stream>>>(y_bf, Wp_bf, (float*)d_out, BT_, DIM_, DIM_);
}